// Round 1
// baseline (723.318 us; speedup 1.0000x reference)
//
#include <hip/hip_runtime.h>
#include <stdint.h>

#define FIN 128

// ---------------- edge dtype detection ----------------
// Reference declares edge_index as int64. Harness contract says "integer -> int*".
// Detect at runtime: if the buffer is int64 (values < 2^31), every odd 32-bit
// word is 0. If any sampled odd word is nonzero -> int32 layout.
__global__ __launch_bounds__(256) void detect_kernel(const int* __restrict__ ei32,
                                                     int* __restrict__ flag, int nsamp) {
    int i = blockIdx.x * 256 + threadIdx.x;
    if (i < nsamp) {
        if (ei32[2 * i + 1] != 0) atomicOr(flag, 1);
    }
}

__device__ __forceinline__ int edge_at(const void* ei, long long idx, int is32) {
    return is32 ? ((const int*)ei)[idx] : (int)((const long long*)ei)[idx];
}

// ---------------- degree count ----------------
__global__ __launch_bounds__(256) void count_kernel(const void* __restrict__ ei,
                                                    const int* __restrict__ flag,
                                                    int* __restrict__ cnt, int E) {
    int e = blockIdx.x * 256 + threadIdx.x;
    if (e >= E) return;
    int is32 = *flag;
    int d = edge_at(ei, (long long)E + e, is32);
    atomicAdd(&cnt[d], 1);
}

// ---------------- 3-phase scan (inclusive) ----------------
#define SCAN_BS 1024
__global__ __launch_bounds__(SCAN_BS) void scan_phaseA(const int* __restrict__ cnt,
                                                       int* __restrict__ incl,
                                                       int* __restrict__ bsums, int n) {
    __shared__ int sm[SCAN_BS];
    int gid = blockIdx.x * SCAN_BS + threadIdx.x;
    int v = (gid < n) ? cnt[gid] : 0;
    sm[threadIdx.x] = v;
    __syncthreads();
    for (int off = 1; off < SCAN_BS; off <<= 1) {
        int t = 0;
        if ((int)threadIdx.x >= off) t = sm[threadIdx.x - off];
        __syncthreads();
        sm[threadIdx.x] += t;
        __syncthreads();
    }
    if (gid < n) incl[gid] = sm[threadIdx.x];
    if (threadIdx.x == SCAN_BS - 1) bsums[blockIdx.x] = sm[threadIdx.x];
}

__global__ __launch_bounds__(128) void scan_phaseB(int* __restrict__ bsums, int nb) {
    __shared__ int sm[128];
    int v = ((int)threadIdx.x < nb) ? bsums[threadIdx.x] : 0;
    sm[threadIdx.x] = v;
    __syncthreads();
    for (int off = 1; off < 128; off <<= 1) {
        int t = 0;
        if ((int)threadIdx.x >= off) t = sm[threadIdx.x - off];
        __syncthreads();
        sm[threadIdx.x] += t;
        __syncthreads();
    }
    if ((int)threadIdx.x < nb)
        bsums[threadIdx.x] = (threadIdx.x == 0) ? 0 : sm[threadIdx.x - 1];
}

__global__ __launch_bounds__(256) void scan_phaseC(int* __restrict__ incl,
                                                   const int* __restrict__ bsums, int n) {
    int gid = blockIdx.x * 256 + threadIdx.x;
    if (gid < n) incl[gid] += bsums[gid >> 10];
}

// ---------------- dinv = rsqrt(deg), deg = cnt + 1 (self loop) ----------------
__global__ __launch_bounds__(256) void dinv_kernel(const int* __restrict__ cnt,
                                                   float* __restrict__ dinv, int n) {
    int i = blockIdx.x * 256 + threadIdx.x;
    if (i < n) dinv[i] = rsqrtf((float)cnt[i] + 1.0f);
}

// ---------------- CSR fill ----------------
__global__ __launch_bounds__(256) void fill_kernel(const void* __restrict__ ei,
                                                   const int* __restrict__ flag,
                                                   const int* __restrict__ rowend,
                                                   const int* __restrict__ cnt,
                                                   int* __restrict__ fillc,
                                                   int* __restrict__ col, int E) {
    int e = blockIdx.x * 256 + threadIdx.x;
    if (e >= E) return;
    int is32 = *flag;
    int s = edge_at(ei, e, is32);
    int d = edge_at(ei, (long long)E + e, is32);
    int pos = rowend[d] - cnt[d] + atomicAdd(&fillc[d], 1);
    col[pos] = s;
}

// ---------------- fp32 GEMM: C[n x NCOL] = A[n x 128] @ W[128 x NCOL] ----------------
// block: 256 threads, tile 64 rows x NCOL cols; per-thread 4 rows x CPT cols.
// Asub padded to stride 33 so the 4 broadcast reads per k hit distinct banks.
template <int NCOL, int CPT>
__global__ __launch_bounds__(256) void gemm_k128(const float* __restrict__ A,
                                                 const float* __restrict__ W,
                                                 float* __restrict__ C, int n) {
    __shared__ float Asub[64 * 33];
    __shared__ float Wsub[32 * NCOL];
    const int t = threadIdx.x;
    const int tc = t & 15;   // thread col group
    const int tr = t >> 4;   // thread row group
    const int row0 = blockIdx.x * 64;

    float acc[4][CPT];
#pragma unroll
    for (int i = 0; i < 4; ++i)
#pragma unroll
        for (int c = 0; c < CPT; ++c) acc[i][c] = 0.0f;

    for (int kc = 0; kc < 128; kc += 32) {
        // stage A chunk (64 rows x 32 k), transposed-free row-major, stride 33
#pragma unroll
        for (int i = 0; i < 2; ++i) {
            int s = t + i * 256;          // 0..511
            int r = s >> 3, kq = s & 7;   // 8 float4 per row
            int gr = row0 + r;
            gr = gr < n ? gr : n - 1;
            float4 v = *(const float4*)(A + (size_t)gr * FIN + kc + kq * 4);
            Asub[r * 33 + kq * 4 + 0] = v.x;
            Asub[r * 33 + kq * 4 + 1] = v.y;
            Asub[r * 33 + kq * 4 + 2] = v.z;
            Asub[r * 33 + kq * 4 + 3] = v.w;
        }
        // stage W chunk (32 k x NCOL)
#pragma unroll
        for (int i = 0; i < NCOL / 32; ++i) {
            int s = t + i * 256;          // 0 .. 8*NCOL-1
            int k = s / (NCOL / 4);
            int cq = s % (NCOL / 4);
            *(float4*)(Wsub + k * NCOL + cq * 4) =
                *(const float4*)(W + (size_t)(kc + k) * NCOL + cq * 4);
        }
        __syncthreads();
#pragma unroll 8
        for (int k = 0; k < 32; ++k) {
            float b[CPT];
            {
                float4 b0 = *(const float4*)(Wsub + k * NCOL + tc * 4);
                b[0] = b0.x; b[1] = b0.y; b[2] = b0.z; b[3] = b0.w;
                if (CPT == 8) {
                    float4 b1 = *(const float4*)(Wsub + k * NCOL + 64 + tc * 4);
                    b[4] = b1.x; b[5] = b1.y; b[6] = b1.z; b[7] = b1.w;
                }
            }
            float a[4];
#pragma unroll
            for (int i = 0; i < 4; ++i) a[i] = Asub[(tr * 4 + i) * 33 + k];
#pragma unroll
            for (int i = 0; i < 4; ++i)
#pragma unroll
                for (int c = 0; c < CPT; ++c) acc[i][c] += a[i] * b[c];
        }
        __syncthreads();
    }
#pragma unroll
    for (int i = 0; i < 4; ++i) {
        int gr = row0 + tr * 4 + i;
        if (gr < n) {
            float4 v0 = make_float4(acc[i][0], acc[i][1], acc[i][2], acc[i][3]);
            *(float4*)(C + (size_t)gr * NCOL + tc * 4) = v0;
            if (CPT == 8) {
                float4 v1 = make_float4(acc[i][4], acc[i][5], acc[i][6], acc[i][7]);
                *(float4*)(C + (size_t)gr * NCOL + 64 + tc * 4) = v1;
            }
        }
    }
}

// ---------------- aggregation, width 128: out = relu?(dinv[i]*sum + b) ----------------
// one wave per node; lane f and f+64
__global__ __launch_bounds__(256) void agg_relu_128(const float* __restrict__ T,
                                                    const int* __restrict__ rowend,
                                                    const int* __restrict__ cnt,
                                                    const int* __restrict__ col,
                                                    const float* __restrict__ dinv,
                                                    const float* __restrict__ bias,
                                                    float* __restrict__ out, int n,
                                                    int do_relu) {
    int node = blockIdx.x * 4 + (threadIdx.x >> 6);
    if (node >= n) return;
    int lane = threadIdx.x & 63;
    int end = rowend[node];
    int start = end - cnt[node];
    float di = dinv[node];
    // self loop: dinv[i]^2 * T[i]  (outer di applied at the end)
    float acc0 = T[(size_t)node * 128 + lane] * di;
    float acc1 = T[(size_t)node * 128 + 64 + lane] * di;
    int p = start;
    for (; p + 4 <= end; p += 4) {
        int s0 = col[p], s1 = col[p + 1], s2 = col[p + 2], s3 = col[p + 3];
        float w0 = dinv[s0], w1 = dinv[s1], w2 = dinv[s2], w3 = dinv[s3];
        const float* r0 = T + (size_t)s0 * 128;
        const float* r1 = T + (size_t)s1 * 128;
        const float* r2 = T + (size_t)s2 * 128;
        const float* r3 = T + (size_t)s3 * 128;
        acc0 += w0 * r0[lane];      acc1 += w0 * r0[64 + lane];
        acc0 += w1 * r1[lane];      acc1 += w1 * r1[64 + lane];
        acc0 += w2 * r2[lane];      acc1 += w2 * r2[64 + lane];
        acc0 += w3 * r3[lane];      acc1 += w3 * r3[64 + lane];
    }
    for (; p < end; ++p) {
        int s = col[p];
        float w = dinv[s];
        const float* r = T + (size_t)s * 128;
        acc0 += w * r[lane];
        acc1 += w * r[64 + lane];
    }
    float v0 = di * acc0 + bias[lane];
    float v1 = di * acc1 + bias[64 + lane];
    if (do_relu) { v0 = fmaxf(v0, 0.0f); v1 = fmaxf(v1, 0.0f); }
    out[(size_t)node * 128 + lane] = v0;
    out[(size_t)node * 128 + 64 + lane] = v1;
}

// ---------------- aggregation width 64 + bias + log_softmax ----------------
__global__ __launch_bounds__(256) void agg_lsm_64(const float* __restrict__ T,
                                                  const int* __restrict__ rowend,
                                                  const int* __restrict__ cnt,
                                                  const int* __restrict__ col,
                                                  const float* __restrict__ dinv,
                                                  const float* __restrict__ bias,
                                                  float* __restrict__ out, int n) {
    int node = blockIdx.x * 4 + (threadIdx.x >> 6);
    if (node >= n) return;
    int lane = threadIdx.x & 63;
    int end = rowend[node];
    int start = end - cnt[node];
    float di = dinv[node];
    float acc = T[(size_t)node * 64 + lane] * di;
    int p = start;
    for (; p + 4 <= end; p += 4) {
        int s0 = col[p], s1 = col[p + 1], s2 = col[p + 2], s3 = col[p + 3];
        float w0 = dinv[s0], w1 = dinv[s1], w2 = dinv[s2], w3 = dinv[s3];
        acc += w0 * T[(size_t)s0 * 64 + lane];
        acc += w1 * T[(size_t)s1 * 64 + lane];
        acc += w2 * T[(size_t)s2 * 64 + lane];
        acc += w3 * T[(size_t)s3 * 64 + lane];
    }
    for (; p < end; ++p) {
        int s = col[p];
        acc += dinv[s] * T[(size_t)s * 64 + lane];
    }
    float r = di * acc + bias[lane];
    // log_softmax across the 64 lanes
    float m = r;
    for (int o = 32; o > 0; o >>= 1) m = fmaxf(m, __shfl_xor(m, o, 64));
    float e = expf(r - m);
    float ssum = e;
    for (int o = 32; o > 0; o >>= 1) ssum += __shfl_xor(ssum, o, 64);
    out[(size_t)node * 64 + lane] = r - m - logf(ssum);
}

// ---------------- launcher ----------------
extern "C" void kernel_launch(void* const* d_in, const int* in_sizes, int n_in,
                              void* d_out, int out_size, void* d_ws, size_t ws_size,
                              hipStream_t stream) {
    const float* x  = (const float*)d_in[0];
    const void*  ei = d_in[1];
    const float* W1 = (const float*)d_in[2];
    const float* b1 = (const float*)d_in[3];
    const float* W2 = (const float*)d_in[4];
    const float* b2 = (const float*)d_in[5];
    const float* W3 = (const float*)d_in[6];
    const float* b3 = (const float*)d_in[7];
    float* out = (float*)d_out;

    const int n = in_sizes[0] / FIN;       // 100000
    const int E = in_sizes[1] / 2;         // 1600000

    // workspace carve (256B aligned)
    char* p = (char*)d_ws;
    auto carve = [&](size_t bytes) {
        char* q = p;
        p += (bytes + 255) & ~(size_t)255;
        return q;
    };
    int*   cnt    = (int*)carve((size_t)n * 4);
    int*   fillc  = (int*)carve((size_t)n * 4);
    int*   flag   = (int*)carve(256);
    int*   rowend = (int*)carve((size_t)n * 4);
    int*   bsums  = (int*)carve(1024 * 4);
    float* dinv   = (float*)carve((size_t)n * 4);
    int*   colb   = (int*)carve((size_t)E * 4);
    float* T      = (float*)carve((size_t)n * 128 * 4);
    float* Hb     = (float*)carve((size_t)n * 128 * 4);

    hipMemsetAsync(cnt, 0, (size_t)n * 4, stream);
    hipMemsetAsync(fillc, 0, (size_t)n * 4, stream);
    hipMemsetAsync(flag, 0, 4, stream);

    const int gE = (E + 255) / 256;
    const int g256 = (n + 255) / 256;
    const int nbA = (n + SCAN_BS - 1) / SCAN_BS;
    const int gagg = (n + 3) / 4;
    const int ggemm = (n + 63) / 64;
    const int nsamp = E < 65536 ? E : 65536;

    detect_kernel<<<(nsamp + 255) / 256, 256, 0, stream>>>((const int*)ei, flag, nsamp);
    count_kernel<<<gE, 256, 0, stream>>>(ei, flag, cnt, E);
    scan_phaseA<<<nbA, SCAN_BS, 0, stream>>>(cnt, rowend, bsums, n);
    scan_phaseB<<<1, 128, 0, stream>>>(bsums, nbA);
    scan_phaseC<<<g256, 256, 0, stream>>>(rowend, bsums, n);
    dinv_kernel<<<g256, 256, 0, stream>>>(cnt, dinv, n);
    fill_kernel<<<gE, 256, 0, stream>>>(ei, flag, rowend, cnt, fillc, colb, E);

    // layer 1: T = x @ W1 ; Hb = relu(agg(T) + b1)
    gemm_k128<128, 8><<<ggemm, 256, 0, stream>>>(x, W1, T, n);
    agg_relu_128<<<gagg, 256, 0, stream>>>(T, rowend, cnt, colb, dinv, b1, Hb, n, 1);
    // layer 2: T = Hb @ W2 ; Hb = relu(agg(T) + b2)
    gemm_k128<128, 8><<<ggemm, 256, 0, stream>>>(Hb, W2, T, n);
    agg_relu_128<<<gagg, 256, 0, stream>>>(T, rowend, cnt, colb, dinv, b2, Hb, n, 1);
    // layer 3: T = Hb @ W3 (64 cols, GEMM first since aggregation is linear);
    // out = log_softmax(agg(T) + b3)
    gemm_k128<64, 4><<<ggemm, 256, 0, stream>>>(Hb, W3, T, n);
    agg_lsm_64<<<gagg, 256, 0, stream>>>(T, rowend, cnt, colb, dinv, b3, out, n);
}

// Round 2
// 622.733 us; speedup vs baseline: 1.1615x; 1.1615x over previous
//
#include <hip/hip_runtime.h>
#include <stdint.h>

#define FIN 128

// ---------------- bf16 helpers (manual, RNE) ----------------
__device__ __forceinline__ float2 bf2_to_f2(uint32_t u) {
    union { uint32_t i; float f; } a, b;
    a.i = (u & 0xFFFFu) << 16;
    b.i = u & 0xFFFF0000u;
    return make_float2(a.f, b.f);
}
__device__ __forceinline__ uint32_t f2_to_bf2(float x, float y) {
    union { float f; uint32_t i; } a, b;
    a.f = x; b.f = y;
    uint32_t ax = a.i + 0x7FFF + ((a.i >> 16) & 1);
    uint32_t by = b.i + 0x7FFF + ((b.i >> 16) & 1);
    return (ax >> 16) | (by & 0xFFFF0000u);
}

// ---------------- edge dtype detection ----------------
__global__ __launch_bounds__(256) void detect_kernel(const int* __restrict__ ei32,
                                                     int* __restrict__ flag, int nsamp) {
    int i = blockIdx.x * 256 + threadIdx.x;
    if (i < nsamp) {
        if (ei32[2 * i + 1] != 0) atomicOr(flag, 1);
    }
}

__device__ __forceinline__ int edge_at(const void* ei, long long idx, int is32) {
    return is32 ? ((const int*)ei)[idx] : (int)((const long long*)ei)[idx];
}

// ---------------- degree count ----------------
__global__ __launch_bounds__(256) void count_kernel(const void* __restrict__ ei,
                                                    const int* __restrict__ flag,
                                                    int* __restrict__ cnt, int E) {
    int e = blockIdx.x * 256 + threadIdx.x;
    if (e >= E) return;
    int is32 = *flag;
    int d = edge_at(ei, (long long)E + e, is32);
    atomicAdd(&cnt[d], 1);
}

// ---------------- 3-phase scan (inclusive) ----------------
#define SCAN_BS 1024
__global__ __launch_bounds__(SCAN_BS) void scan_phaseA(const int* __restrict__ cnt,
                                                       int* __restrict__ incl,
                                                       int* __restrict__ bsums, int n) {
    __shared__ int sm[SCAN_BS];
    int gid = blockIdx.x * SCAN_BS + threadIdx.x;
    int v = (gid < n) ? cnt[gid] : 0;
    sm[threadIdx.x] = v;
    __syncthreads();
    for (int off = 1; off < SCAN_BS; off <<= 1) {
        int t = 0;
        if ((int)threadIdx.x >= off) t = sm[threadIdx.x - off];
        __syncthreads();
        sm[threadIdx.x] += t;
        __syncthreads();
    }
    if (gid < n) incl[gid] = sm[threadIdx.x];
    if (threadIdx.x == SCAN_BS - 1) bsums[blockIdx.x] = sm[threadIdx.x];
}

__global__ __launch_bounds__(128) void scan_phaseB(int* __restrict__ bsums, int nb) {
    __shared__ int sm[128];
    int v = ((int)threadIdx.x < nb) ? bsums[threadIdx.x] : 0;
    sm[threadIdx.x] = v;
    __syncthreads();
    for (int off = 1; off < 128; off <<= 1) {
        int t = 0;
        if ((int)threadIdx.x >= off) t = sm[threadIdx.x - off];
        __syncthreads();
        sm[threadIdx.x] += t;
        __syncthreads();
    }
    if ((int)threadIdx.x < nb)
        bsums[threadIdx.x] = (threadIdx.x == 0) ? 0 : sm[threadIdx.x - 1];
}

__global__ __launch_bounds__(256) void scan_phaseC(int* __restrict__ incl,
                                                   const int* __restrict__ bsums, int n) {
    int gid = blockIdx.x * 256 + threadIdx.x;
    if (gid < n) incl[gid] += bsums[gid >> 10];
}

// ---------------- dinv = rsqrt(deg), deg = cnt + 1 (self loop) ----------------
__global__ __launch_bounds__(256) void dinv_kernel(const int* __restrict__ cnt,
                                                   float* __restrict__ dinv, int n) {
    int i = blockIdx.x * 256 + threadIdx.x;
    if (i < n) dinv[i] = rsqrtf((float)cnt[i] + 1.0f);
}

// ---------------- CSR fill ----------------
__global__ __launch_bounds__(256) void fill_kernel(const void* __restrict__ ei,
                                                   const int* __restrict__ flag,
                                                   const int* __restrict__ rowend,
                                                   const int* __restrict__ cnt,
                                                   int* __restrict__ fillc,
                                                   int* __restrict__ col, int E) {
    int e = blockIdx.x * 256 + threadIdx.x;
    if (e >= E) return;
    int is32 = *flag;
    int s = edge_at(ei, e, is32);
    int d = edge_at(ei, (long long)E + e, is32);
    int pos = rowend[d] - cnt[d] + atomicAdd(&fillc[d], 1);
    col[pos] = s;
}

// ---------------- fp32 GEMM: C[n x NCOL] = A[n x 128] @ W[128 x NCOL] ----------------
// block 256, tile 64 x NCOL, per-thread 4 x CPT. Asub stride 33 (bank-safe).
// OUT_BF16: epilogue packs bf16 (halves store traffic + downstream gather bytes).
template <int NCOL, int CPT, int OUT_BF16>
__global__ __launch_bounds__(256) void gemm_k128(const float* __restrict__ A,
                                                 const float* __restrict__ W,
                                                 void* __restrict__ Cv, int n) {
    __shared__ float Asub[64 * 33];
    __shared__ float Wsub[32 * NCOL];
    const int t = threadIdx.x;
    const int tc = t & 15;
    const int tr = t >> 4;
    const int row0 = blockIdx.x * 64;

    float acc[4][CPT];
#pragma unroll
    for (int i = 0; i < 4; ++i)
#pragma unroll
        for (int c = 0; c < CPT; ++c) acc[i][c] = 0.0f;

    for (int kc = 0; kc < 128; kc += 32) {
#pragma unroll
        for (int i = 0; i < 2; ++i) {
            int s = t + i * 256;
            int r = s >> 3, kq = s & 7;
            int gr = row0 + r;
            gr = gr < n ? gr : n - 1;
            float4 v = *(const float4*)(A + (size_t)gr * FIN + kc + kq * 4);
            Asub[r * 33 + kq * 4 + 0] = v.x;
            Asub[r * 33 + kq * 4 + 1] = v.y;
            Asub[r * 33 + kq * 4 + 2] = v.z;
            Asub[r * 33 + kq * 4 + 3] = v.w;
        }
#pragma unroll
        for (int i = 0; i < NCOL / 32; ++i) {
            int s = t + i * 256;
            int k = s / (NCOL / 4);
            int cq = s % (NCOL / 4);
            *(float4*)(Wsub + k * NCOL + cq * 4) =
                *(const float4*)(W + (size_t)(kc + k) * NCOL + cq * 4);
        }
        __syncthreads();
#pragma unroll 8
        for (int k = 0; k < 32; ++k) {
            float b[CPT];
            {
                float4 b0 = *(const float4*)(Wsub + k * NCOL + tc * 4);
                b[0] = b0.x; b[1] = b0.y; b[2] = b0.z; b[3] = b0.w;
                if (CPT == 8) {
                    float4 b1 = *(const float4*)(Wsub + k * NCOL + 64 + tc * 4);
                    b[4] = b1.x; b[5] = b1.y; b[6] = b1.z; b[7] = b1.w;
                }
            }
            float a[4];
#pragma unroll
            for (int i = 0; i < 4; ++i) a[i] = Asub[(tr * 4 + i) * 33 + k];
#pragma unroll
            for (int i = 0; i < 4; ++i)
#pragma unroll
                for (int c = 0; c < CPT; ++c) acc[i][c] += a[i] * b[c];
        }
        __syncthreads();
    }
#pragma unroll
    for (int i = 0; i < 4; ++i) {
        int gr = row0 + tr * 4 + i;
        if (gr >= n) continue;
        if (OUT_BF16) {
            unsigned short* C = (unsigned short*)Cv;
            uint2 v0;
            v0.x = f2_to_bf2(acc[i][0], acc[i][1]);
            v0.y = f2_to_bf2(acc[i][2], acc[i][3]);
            *(uint2*)(C + (size_t)gr * NCOL + tc * 4) = v0;
            if (CPT == 8) {
                uint2 v1;
                v1.x = f2_to_bf2(acc[i][4], acc[i][5]);
                v1.y = f2_to_bf2(acc[i][6], acc[i][7]);
                *(uint2*)(C + (size_t)gr * NCOL + 64 + tc * 4) = v1;
            }
        } else {
            float* C = (float*)Cv;
            float4 v0 = make_float4(acc[i][0], acc[i][1], acc[i][2], acc[i][3]);
            *(float4*)(C + (size_t)gr * NCOL + tc * 4) = v0;
            if (CPT == 8) {
                float4 v1 = make_float4(acc[i][4], acc[i][5], acc[i][6], acc[i][7]);
                *(float4*)(C + (size_t)gr * NCOL + 64 + tc * 4) = v1;
            }
        }
    }
}

// ---------------- aggregation, width 128, bf16 T: out = relu?(dinv*sum + b) ----------------
// one wave per node; lane handles features 2*lane, 2*lane+1 (one bf16x2 dword per row)
__global__ __launch_bounds__(256) void agg_relu_128_bf16(
        const unsigned short* __restrict__ T, const int* __restrict__ rowend,
        const int* __restrict__ cnt, const int* __restrict__ col,
        const float* __restrict__ dinv, const float* __restrict__ bias,
        float* __restrict__ out, int n, int do_relu) {
    int node = blockIdx.x * 4 + (threadIdx.x >> 6);
    if (node >= n) return;
    int lane = threadIdx.x & 63;
    int end = rowend[node];
    int start = end - cnt[node];
    float di = dinv[node];
    float2 sv = bf2_to_f2(((const uint32_t*)(T + (size_t)node * 128))[lane]);
    float acc0 = sv.x * di;   // self-loop (outer di applied at end)
    float acc1 = sv.y * di;
    int p = start;
    for (; p + 8 <= end; p += 8) {
        int s0 = col[p + 0], s1 = col[p + 1], s2 = col[p + 2], s3 = col[p + 3];
        int s4 = col[p + 4], s5 = col[p + 5], s6 = col[p + 6], s7 = col[p + 7];
        float w0 = dinv[s0], w1 = dinv[s1], w2 = dinv[s2], w3 = dinv[s3];
        float w4 = dinv[s4], w5 = dinv[s5], w6 = dinv[s6], w7 = dinv[s7];
        uint32_t u0 = ((const uint32_t*)(T + (size_t)s0 * 128))[lane];
        uint32_t u1 = ((const uint32_t*)(T + (size_t)s1 * 128))[lane];
        uint32_t u2 = ((const uint32_t*)(T + (size_t)s2 * 128))[lane];
        uint32_t u3 = ((const uint32_t*)(T + (size_t)s3 * 128))[lane];
        uint32_t u4 = ((const uint32_t*)(T + (size_t)s4 * 128))[lane];
        uint32_t u5 = ((const uint32_t*)(T + (size_t)s5 * 128))[lane];
        uint32_t u6 = ((const uint32_t*)(T + (size_t)s6 * 128))[lane];
        uint32_t u7 = ((const uint32_t*)(T + (size_t)s7 * 128))[lane];
        float2 v;
        v = bf2_to_f2(u0); acc0 += w0 * v.x; acc1 += w0 * v.y;
        v = bf2_to_f2(u1); acc0 += w1 * v.x; acc1 += w1 * v.y;
        v = bf2_to_f2(u2); acc0 += w2 * v.x; acc1 += w2 * v.y;
        v = bf2_to_f2(u3); acc0 += w3 * v.x; acc1 += w3 * v.y;
        v = bf2_to_f2(u4); acc0 += w4 * v.x; acc1 += w4 * v.y;
        v = bf2_to_f2(u5); acc0 += w5 * v.x; acc1 += w5 * v.y;
        v = bf2_to_f2(u6); acc0 += w6 * v.x; acc1 += w6 * v.y;
        v = bf2_to_f2(u7); acc0 += w7 * v.x; acc1 += w7 * v.y;
    }
    for (; p < end; ++p) {
        int s = col[p];
        float w = dinv[s];
        float2 v = bf2_to_f2(((const uint32_t*)(T + (size_t)s * 128))[lane]);
        acc0 += w * v.x;
        acc1 += w * v.y;
    }
    float2 b2 = ((const float2*)bias)[lane];
    float v0 = di * acc0 + b2.x;
    float v1 = di * acc1 + b2.y;
    if (do_relu) { v0 = fmaxf(v0, 0.0f); v1 = fmaxf(v1, 0.0f); }
    *(float2*)(out + (size_t)node * 128 + 2 * lane) = make_float2(v0, v1);
}

// ---------------- aggregation width 64 (fp32 T) + bias + log_softmax ----------------
__global__ __launch_bounds__(256) void agg_lsm_64(const float* __restrict__ T,
                                                  const int* __restrict__ rowend,
                                                  const int* __restrict__ cnt,
                                                  const int* __restrict__ col,
                                                  const float* __restrict__ dinv,
                                                  const float* __restrict__ bias,
                                                  float* __restrict__ out, int n) {
    int node = blockIdx.x * 4 + (threadIdx.x >> 6);
    if (node >= n) return;
    int lane = threadIdx.x & 63;
    int end = rowend[node];
    int start = end - cnt[node];
    float di = dinv[node];
    float acc = T[(size_t)node * 64 + lane] * di;
    int p = start;
    for (; p + 4 <= end; p += 4) {
        int s0 = col[p], s1 = col[p + 1], s2 = col[p + 2], s3 = col[p + 3];
        float w0 = dinv[s0], w1 = dinv[s1], w2 = dinv[s2], w3 = dinv[s3];
        acc += w0 * T[(size_t)s0 * 64 + lane];
        acc += w1 * T[(size_t)s1 * 64 + lane];
        acc += w2 * T[(size_t)s2 * 64 + lane];
        acc += w3 * T[(size_t)s3 * 64 + lane];
    }
    for (; p < end; ++p) {
        int s = col[p];
        acc += dinv[s] * T[(size_t)s * 64 + lane];
    }
    float r = di * acc + bias[lane];
    float m = r;
    for (int o = 32; o > 0; o >>= 1) m = fmaxf(m, __shfl_xor(m, o, 64));
    float e = expf(r - m);
    float ssum = e;
    for (int o = 32; o > 0; o >>= 1) ssum += __shfl_xor(ssum, o, 64);
    out[(size_t)node * 64 + lane] = r - m - logf(ssum);
}

// ---------------- launcher ----------------
extern "C" void kernel_launch(void* const* d_in, const int* in_sizes, int n_in,
                              void* d_out, int out_size, void* d_ws, size_t ws_size,
                              hipStream_t stream) {
    const float* x  = (const float*)d_in[0];
    const void*  ei = d_in[1];
    const float* W1 = (const float*)d_in[2];
    const float* b1 = (const float*)d_in[3];
    const float* W2 = (const float*)d_in[4];
    const float* b2 = (const float*)d_in[5];
    const float* W3 = (const float*)d_in[6];
    const float* b3 = (const float*)d_in[7];
    float* out = (float*)d_out;

    const int n = in_sizes[0] / FIN;       // 100000
    const int E = in_sizes[1] / 2;         // 1600000

    char* p = (char*)d_ws;
    auto carve = [&](size_t bytes) {
        char* q = p;
        p += (bytes + 255) & ~(size_t)255;
        return q;
    };
    int*   cnt    = (int*)carve((size_t)n * 4);
    int*   fillc  = (int*)carve((size_t)n * 4);
    int*   flag   = (int*)carve(256);
    int*   rowend = (int*)carve((size_t)n * 4);
    int*   bsums  = (int*)carve(1024 * 4);
    float* dinv   = (float*)carve((size_t)n * 4);
    int*   colb   = (int*)carve((size_t)E * 4);
    // T: bf16 n*128 (25.6MB) for layers 1-2; reused as fp32 n*64 (25.6MB) for layer 3
    void*  T      = (void*)carve((size_t)n * 128 * 2 > (size_t)n * 64 * 4
                                     ? (size_t)n * 128 * 2 : (size_t)n * 64 * 4);
    float* Hb     = (float*)carve((size_t)n * 128 * 4);

    hipMemsetAsync(cnt, 0, (size_t)n * 4, stream);
    hipMemsetAsync(fillc, 0, (size_t)n * 4, stream);
    hipMemsetAsync(flag, 0, 4, stream);

    const int gE = (E + 255) / 256;
    const int g256 = (n + 255) / 256;
    const int nbA = (n + SCAN_BS - 1) / SCAN_BS;
    const int gagg = (n + 3) / 4;
    const int ggemm = (n + 63) / 64;
    const int nsamp = E < 65536 ? E : 65536;

    detect_kernel<<<(nsamp + 255) / 256, 256, 0, stream>>>((const int*)ei, flag, nsamp);
    count_kernel<<<gE, 256, 0, stream>>>(ei, flag, cnt, E);
    scan_phaseA<<<nbA, SCAN_BS, 0, stream>>>(cnt, rowend, bsums, n);
    scan_phaseB<<<1, 128, 0, stream>>>(bsums, nbA);
    scan_phaseC<<<g256, 256, 0, stream>>>(rowend, bsums, n);
    dinv_kernel<<<g256, 256, 0, stream>>>(cnt, dinv, n);
    fill_kernel<<<gE, 256, 0, stream>>>(ei, flag, rowend, cnt, fillc, colb, E);

    // layer 1: T(bf16) = x @ W1 ; Hb = relu(agg(T) + b1)
    gemm_k128<128, 8, 1><<<ggemm, 256, 0, stream>>>(x, W1, T, n);
    agg_relu_128_bf16<<<gagg, 256, 0, stream>>>((const unsigned short*)T, rowend, cnt,
                                                colb, dinv, b1, Hb, n, 1);
    // layer 2: T(bf16) = Hb @ W2 ; Hb = relu(agg(T) + b2)
    gemm_k128<128, 8, 1><<<ggemm, 256, 0, stream>>>(Hb, W2, T, n);
    agg_relu_128_bf16<<<gagg, 256, 0, stream>>>((const unsigned short*)T, rowend, cnt,
                                                colb, dinv, b2, Hb, n, 1);
    // layer 3: T(fp32) = Hb @ W3 ; out = log_softmax(agg(T) + b3)
    gemm_k128<64, 4, 0><<<ggemm, 256, 0, stream>>>(Hb, W3, T, n);
    agg_lsm_64<<<gagg, 256, 0, stream>>>((const float*)T, rowend, cnt, colb, dinv, b3,
                                         out, n);
}